// Round 10
// baseline (244.837 us; speedup 1.0000x reference)
//
#include <hip/hip_runtime.h>
#include <math.h>

#define C_DIM 128
#define KNN 8
#define NPTS 8192
#define M_TOTAL 16384   // B*N
#define CHUNK 1024      // points staged in LDS per iteration of the KNN scan
#define CAND_CAP 96     // per-query candidate buffer (expected use: ~25-35)

typedef unsigned long long u64;

// ---------------------------------------------------------------------------
// Kernel 1: coords -> packed float4 {x, y, z, |p|^2} per point
// ---------------------------------------------------------------------------
__global__ __launch_bounds__(256) void prep_coords(
    const float* __restrict__ coords, float4* __restrict__ c4) {
  int g = blockIdx.x * 256 + threadIdx.x;
  if (g < M_TOTAL) {
    float x = coords[3 * g + 0];
    float y = coords[3 * g + 1];
    float z = coords[3 * g + 2];
    // same fma ordering as the scan's dot product so self-distance cancels
    // to exactly 0.0f
    float s = fmaf(x, x, fmaf(y, y, z * z));
    c4[g] = make_float4(x, y, z, s);
  }
}

// ---------------------------------------------------------------------------
// Kernel 2: transpose the four 128x128 weight matrices once: WT[c][o]=W[o][c]
// ---------------------------------------------------------------------------
__global__ __launch_bounds__(256) void transpose_w(
    const float* __restrict__ Wq, const float* __restrict__ Wk,
    const float* __restrict__ Wv, const float* __restrict__ Wo,
    float* __restrict__ Tq, float* __restrict__ Tk,
    float* __restrict__ Tv, float* __restrict__ To) {
  int g = blockIdx.x * 256 + threadIdx.x;
  int mat = g >> 14;          // 0..3
  int j = g & 16383;          // dest linear index: j = c*128 + o
  int c = j >> 7, o = j & 127;
  const float* src = (mat == 0) ? Wq : (mat == 1) ? Wk : (mat == 2) ? Wv : Wo;
  float* dst = (mat == 0) ? Tq : (mat == 1) ? Tk : (mat == 2) ? Tv : To;
  dst[j] = src[o * C_DIM + c];   // coalesced write, strided (L2-hit) read
}

// ---------------------------------------------------------------------------
__device__ __forceinline__ void stage_x64(
    float (*Xs)[132], const float* __restrict__ X, int row0, int t) {
  const float4* X4 = (const float4*)(X + (size_t)row0 * C_DIM);
  for (int i = t; i < 64 * 32; i += 256) {
    int r = i >> 5, c4i = i & 31;
    *(float4*)&Xs[r][c4i * 4] = X4[i];
  }
}

// ---------------------------------------------------------------------------
// Kernel 3a: fused q/k/v projection, split-N: 512 blocks, each 64 rows x
// 64 output cols (2 blocks/CU -> 2 waves/SIMD latency hiding; R7's 256-block
// config was 1 wave/SIMD, stall-dominated). 4 rows x 4 cols x 3 mats/thread.
// Per-output FMA order unchanged (ascending c) -> results bitwise identical.
// ---------------------------------------------------------------------------
__global__ __launch_bounds__(256) void gemm_qkv(
    const float* __restrict__ X,
    const float* __restrict__ WTq, const float* __restrict__ WTk,
    const float* __restrict__ WTv,
    float* __restrict__ Yq, float* __restrict__ Yk, float* __restrict__ Yv) {
  __shared__ float Xs[64][132];
  const int t = threadIdx.x;
  const int row0 = (blockIdx.x >> 1) * 64;
  const int ob = (blockIdx.x & 1) * 64;   // which 64-col half
  stage_x64(Xs, X, row0, t);
  __syncthreads();

  const int r0 = (t >> 4) * 4;
  const int o0 = ob + (t & 15) * 4;

  float aq[4][4], ak[4][4], av[4][4];
#pragma unroll
  for (int i = 0; i < 4; ++i)
#pragma unroll
    for (int j = 0; j < 4; ++j) { aq[i][j] = 0.f; ak[i][j] = 0.f; av[i][j] = 0.f; }

  for (int c = 0; c < C_DIM; c += 4) {
    float xs[4][4];
#pragma unroll
    for (int i = 0; i < 4; ++i) {
      float4 xv = *(const float4*)&Xs[r0 + i][c];
      xs[i][0] = xv.x; xs[i][1] = xv.y; xs[i][2] = xv.z; xs[i][3] = xv.w;
    }
#pragma unroll
    for (int cc = 0; cc < 4; ++cc) {
      const size_t wrow = (size_t)(c + cc) * C_DIM + o0;
      float4 qa = *(const float4*)&WTq[wrow];
      float4 ka = *(const float4*)&WTk[wrow];
      float4 va = *(const float4*)&WTv[wrow];
#pragma unroll
      for (int i = 0; i < 4; ++i) {
        float x = xs[i][cc];
        aq[i][0] = fmaf(x, qa.x, aq[i][0]); aq[i][1] = fmaf(x, qa.y, aq[i][1]);
        aq[i][2] = fmaf(x, qa.z, aq[i][2]); aq[i][3] = fmaf(x, qa.w, aq[i][3]);
        ak[i][0] = fmaf(x, ka.x, ak[i][0]); ak[i][1] = fmaf(x, ka.y, ak[i][1]);
        ak[i][2] = fmaf(x, ka.z, ak[i][2]); ak[i][3] = fmaf(x, ka.w, ak[i][3]);
        av[i][0] = fmaf(x, va.x, av[i][0]); av[i][1] = fmaf(x, va.y, av[i][1]);
        av[i][2] = fmaf(x, va.z, av[i][2]); av[i][3] = fmaf(x, va.w, av[i][3]);
      }
    }
  }

#pragma unroll
  for (int i = 0; i < 4; ++i) {
    const size_t yoff = (size_t)(row0 + r0 + i) * C_DIM + o0;
    *(float4*)&Yq[yoff] = make_float4(aq[i][0], aq[i][1], aq[i][2], aq[i][3]);
    *(float4*)&Yk[yoff] = make_float4(ak[i][0], ak[i][1], ak[i][2], ak[i][3]);
    *(float4*)&Yv[yoff] = make_float4(av[i][0], av[i][1], av[i][2], av[i][3]);
  }
}

// ---------------------------------------------------------------------------
// Kernel 3b: output projection, same split-N scheme (512 blocks).
// ---------------------------------------------------------------------------
__global__ __launch_bounds__(256) void gemm_xwt(
    const float* __restrict__ X, const float* __restrict__ WT,
    float* __restrict__ Y) {
  __shared__ float Xs[64][132];
  const int t = threadIdx.x;
  const int row0 = (blockIdx.x >> 1) * 64;
  const int ob = (blockIdx.x & 1) * 64;
  stage_x64(Xs, X, row0, t);
  __syncthreads();

  const int r0 = (t >> 4) * 4;
  const int o0 = ob + (t & 15) * 4;

  float acc[4][4];
#pragma unroll
  for (int i = 0; i < 4; ++i)
#pragma unroll
    for (int j = 0; j < 4; ++j) acc[i][j] = 0.0f;

  for (int c = 0; c < C_DIM; c += 4) {
    float xs[4][4];
#pragma unroll
    for (int i = 0; i < 4; ++i) {
      float4 xv = *(const float4*)&Xs[r0 + i][c];
      xs[i][0] = xv.x; xs[i][1] = xv.y; xs[i][2] = xv.z; xs[i][3] = xv.w;
    }
#pragma unroll
    for (int cc = 0; cc < 4; ++cc) {
      const size_t wrow = (size_t)(c + cc) * C_DIM + o0;
      float4 wa = *(const float4*)&WT[wrow];
#pragma unroll
      for (int i = 0; i < 4; ++i) {
        float x = xs[i][cc];
        acc[i][0] = fmaf(x, wa.x, acc[i][0]); acc[i][1] = fmaf(x, wa.y, acc[i][1]);
        acc[i][2] = fmaf(x, wa.z, acc[i][2]); acc[i][3] = fmaf(x, wa.w, acc[i][3]);
      }
    }
  }

#pragma unroll
  for (int i = 0; i < 4; ++i) {
    float* yrow = Y + (size_t)(row0 + r0 + i) * C_DIM + o0;
    *(float4*)yrow = make_float4(acc[i][0], acc[i][1], acc[i][2], acc[i][3]);
  }
}

// ---------------------------------------------------------------------------
// Kernel 4: fused KNN + attention, 2 queries/wave, 1.125-PASS scan.
// Phase 1: top-2/lane over CHUNK 0 ONLY -> tau = wave 8th of 128 retained.
//   Subset order stats: tau >= s8(chunk0) >= s8(all) -> safe filter.
// Phase 2: ONE scan of all chunks; d2 <= tau -> ballot-compact (d2,idx)
//   into per-query LDS candidates. After each chunk, tau := min(tau,
//   8th-smallest of candidates) = s8(seen) exactly (candidates contain
//   top-8(seen)); every point is tested against a tau >= s8(all) at its
//   test time -> all true top-8 collected. Final: exact lex-(d2,idx)
//   butterfly-min-pop over candidates (2 keys/lane, handles up to 128).
// ---------------------------------------------------------------------------
__device__ __forceinline__ u64 wave_min_u64(u64 x) {
#pragma unroll
  for (int off = 32; off > 0; off >>= 1) {
    u64 o = __shfl_xor(x, off, 64);
    x = (o < x) ? o : x;
  }
  return x;
}

// wave 8th-smallest over per-lane ascending pairs (u0 <= u1)
__device__ __forceinline__ float wave_8th_of_top2(float u0, float u1) {
  float m = 0.0f;
#pragma unroll
  for (int r = 0; r < KNN; ++r) {
    m = u0;
#pragma unroll
    for (int off = 32; off > 0; off >>= 1) {
      float o = __shfl_xor(m, off, 64);
      m = fminf(m, o);
    }
    bool mine = (u0 == m);   // every lane holding m pops one element
    u0 = mine ? u1 : u0;
    u1 = mine ? INFINITY : u1;
  }
  return m;
}

// tau = wave 8th-smallest d2 among candidates [0, m)
__device__ __forceinline__ float tau_from_cands(
    const u64* __restrict__ cq, int m, int lane) {
  float a = (lane < m) ? __uint_as_float((unsigned)(cq[lane] >> 32)) : INFINITY;
  float b = (lane + 64 < m) ? __uint_as_float((unsigned)(cq[lane + 64] >> 32))
                            : INFINITY;
  return wave_8th_of_top2(fminf(a, b), fmaxf(a, b));
}

__device__ __forceinline__ void attend_one(
    const float4* __restrict__ c4, const float* __restrict__ q,
    const float* __restrict__ k, const float* __restrict__ v,
    float lg, int base, int n, float4 qp, const int (&ni_)[KNN], int lane,
    float* __restrict__ agg) {
  const size_t qrow = (size_t)(base + n) * C_DIM;
  const float qv0 = q[qrow + lane];
  const float qv1 = q[qrow + lane + 64];

  float score[KNN];
#pragma unroll
  for (int j = 0; j < KNN; ++j) {
    const int mj = ni_[j];
    const size_t krow = (size_t)(base + mj) * C_DIM;
    float p = fmaf(qv1, k[krow + lane + 64], qv0 * k[krow + lane]);
#pragma unroll
    for (int off = 32; off > 0; off >>= 1) p += __shfl_xor(p, off, 64);
    // gamma from the diff-based safe norm (reference's second formula)
    const float4 pm = c4[base + mj];
    float dx = qp.x - pm.x, dy = qp.y - pm.y, dz = qp.z - pm.z;
    float d2p = fmaf(dx, dx, fmaf(dy, dy, dz * dz));
    float dist = d2p > 0.0f ? sqrtf(d2p) : 0.0f;
    float gw = expf(lg * dist);
    score[j] = (p / 11.313708498984761f) * gw;   // /sqrt(128) then *gamma
  }

  float mx = score[0];
#pragma unroll
  for (int j = 1; j < KNN; ++j) mx = fmaxf(mx, score[j]);
  float w[KNN]; float sum = 0.0f;
#pragma unroll
  for (int j = 0; j < KNN; ++j) { w[j] = expf(score[j] - mx); sum += w[j]; }
#pragma unroll
  for (int j = 0; j < KNN; ++j) w[j] = w[j] / sum;

  float a0 = 0.0f, a1 = 0.0f;
#pragma unroll
  for (int j = 0; j < KNN; ++j) {
    const size_t vrow = (size_t)(base + ni_[j]) * C_DIM;
    a0 = fmaf(w[j], v[vrow + lane], a0);
    a1 = fmaf(w[j], v[vrow + lane + 64], a1);
  }
  agg[qrow + lane] = a0;
  agg[qrow + lane + 64] = a1;
}

__global__ __launch_bounds__(256) void knn_attn(
    const float4* __restrict__ c4,
    const float* __restrict__ q, const float* __restrict__ k,
    const float* __restrict__ v, const float* __restrict__ log_gamma_p,
    float* __restrict__ agg) {
  __shared__ float4 pts[CHUNK];          // 16 KB
  __shared__ u64 cand[8][CAND_CAP];      // 6 KB, per-query candidate buffers

  const int t = threadIdx.x;
  const int wave = t >> 6;
  const int lane = t & 63;
  const int q0i = blockIdx.x * 8 + wave * 2;     // 8 queries/block; blocks
  const int b = q0i >> 13;                       // never straddle a batch
  const int n0 = q0i & (NPTS - 1);
  const int base = b * NPTS;
  const int w2 = wave * 2;

  const float4 qp0 = c4[base + n0];
  const float4 qp1 = c4[base + n0 + 1];
  const u64 lmask = (1ull << lane) - 1ull;

  // ------------- phase 1: tau from chunk 0 only (top-2/lane) -------------
  for (int i = t; i < CHUNK; i += 256) pts[i] = c4[base + i];
  __syncthreads();

  float m10 = INFINITY, m20 = INFINITY, m11 = INFINITY, m21 = INFINITY;
#pragma unroll
  for (int it = 0; it < CHUNK / 128; ++it) {
    const int ml = it * 128 + lane;
    const float4 pa = pts[ml];
    const float4 pb = pts[ml + 64];
    float dota0 = fmaf(qp0.x, pa.x, fmaf(qp0.y, pa.y, qp0.z * pa.z));
    float dotb0 = fmaf(qp0.x, pb.x, fmaf(qp0.y, pb.y, qp0.z * pb.z));
    float dota1 = fmaf(qp1.x, pa.x, fmaf(qp1.y, pa.y, qp1.z * pa.z));
    float dotb1 = fmaf(qp1.x, pb.x, fmaf(qp1.y, pb.y, qp1.z * pb.z));
    float d2a0 = fmaxf(qp0.w + pa.w - 2.0f * dota0, 0.0f);
    float d2b0 = fmaxf(qp0.w + pb.w - 2.0f * dotb0, 0.0f);
    float d2a1 = fmaxf(qp1.w + pa.w - 2.0f * dota1, 0.0f);
    float d2b1 = fmaxf(qp1.w + pb.w - 2.0f * dotb1, 0.0f);
    float h;
    h = fmaxf(m10, d2a0); m10 = fminf(m10, d2a0); m20 = fminf(m20, h);
    h = fmaxf(m10, d2b0); m10 = fminf(m10, d2b0); m20 = fminf(m20, h);
    h = fmaxf(m11, d2a1); m11 = fminf(m11, d2a1); m21 = fminf(m21, h);
    h = fmaxf(m11, d2b1); m11 = fminf(m11, d2b1); m21 = fminf(m21, h);
  }
  float tau0 = wave_8th_of_top2(m10, m20);
  float tau1 = wave_8th_of_top2(m11, m21);

  // ------------- phase 2: single candidate-collection scan ----------------
  int cnt0 = 0, cnt1 = 0;
  for (int ch = 0; ch < NPTS / CHUNK; ++ch) {
    if (ch > 0) {   // chunk 0 is still resident from phase 1
      __syncthreads();
      for (int i = t; i < CHUNK; i += 256) pts[i] = c4[base + ch * CHUNK + i];
      __syncthreads();
    }

#pragma unroll
    for (int it = 0; it < CHUNK / 128; ++it) {
      const int ml = it * 128 + lane;
      const float4 pa = pts[ml];
      const float4 pb = pts[ml + 64];
      float dota0 = fmaf(qp0.x, pa.x, fmaf(qp0.y, pa.y, qp0.z * pa.z));
      float dotb0 = fmaf(qp0.x, pb.x, fmaf(qp0.y, pb.y, qp0.z * pb.z));
      float dota1 = fmaf(qp1.x, pa.x, fmaf(qp1.y, pa.y, qp1.z * pa.z));
      float dotb1 = fmaf(qp1.x, pb.x, fmaf(qp1.y, pb.y, qp1.z * pb.z));
      float d2a0 = fmaxf(qp0.w + pa.w - 2.0f * dota0, 0.0f);
      float d2b0 = fmaxf(qp0.w + pb.w - 2.0f * dotb0, 0.0f);
      float d2a1 = fmaxf(qp1.w + pa.w - 2.0f * dota1, 0.0f);
      float d2b1 = fmaxf(qp1.w + pb.w - 2.0f * dotb1, 0.0f);
      bool ga0 = d2a0 <= tau0, gb0 = d2b0 <= tau0;
      bool ga1 = d2a1 <= tau1, gb1 = d2b1 <= tau1;
      u64 ma0 = __ballot(ga0), mb0 = __ballot(gb0);
      u64 ma1 = __ballot(ga1), mb1 = __ballot(gb1);
      if (ma0 | mb0 | ma1 | mb1) {   // rarely-taken, wave-uniform branch
        const unsigned ia = (unsigned)(ch * CHUNK + ml);
        if (ga0) {
          int pos = cnt0 + (int)__popcll(ma0 & lmask);
          if (pos < CAND_CAP)
            cand[w2][pos] = ((u64)__float_as_uint(d2a0) << 32) | ia;
        }
        cnt0 += (int)__popcll(ma0);
        if (gb0) {
          int pos = cnt0 + (int)__popcll(mb0 & lmask);
          if (pos < CAND_CAP)
            cand[w2][pos] = ((u64)__float_as_uint(d2b0) << 32) | (ia + 64);
        }
        cnt0 += (int)__popcll(mb0);
        if (ga1) {
          int pos = cnt1 + (int)__popcll(ma1 & lmask);
          if (pos < CAND_CAP)
            cand[w2 + 1][pos] = ((u64)__float_as_uint(d2a1) << 32) | ia;
        }
        cnt1 += (int)__popcll(ma1);
        if (gb1) {
          int pos = cnt1 + (int)__popcll(mb1 & lmask);
          if (pos < CAND_CAP)
            cand[w2 + 1][pos] = ((u64)__float_as_uint(d2b1) << 32) | (ia + 64);
        }
        cnt1 += (int)__popcll(mb1);
      }
    }

    if (ch < NPTS / CHUNK - 1) {   // tighten tau for the remaining chunks
      int m0 = (cnt0 < CAND_CAP) ? cnt0 : CAND_CAP;
      int m1 = (cnt1 < CAND_CAP) ? cnt1 : CAND_CAP;
      tau0 = fminf(tau0, tau_from_cands(cand[w2], m0, lane));
      tau1 = fminf(tau1, tau_from_cands(cand[w2 + 1], m1, lane));
    }
  }

  // ------------- final exact top-8 per query (lex (d2, idx)) -------------
  int ni0_[KNN], ni1_[KNN];
  {
    const int m0 = (cnt0 < CAND_CAP) ? cnt0 : CAND_CAP;
    u64 a = (lane < m0) ? cand[w2][lane] : ~0ull;
    u64 bb = (lane + 64 < m0) ? cand[w2][lane + 64] : ~0ull;
    u64 k0 = (a < bb) ? a : bb, k1 = (a < bb) ? bb : a;
#pragma unroll
    for (int r = 0; r < KNN; ++r) {
      u64 mm = wave_min_u64(k0);
      ni0_[r] = (int)(unsigned)(mm & 0xFFFFFFFFu);
      if (k0 == mm) { k0 = k1; k1 = ~0ull; }   // keys unique: owner pops
    }
    const int m1 = (cnt1 < CAND_CAP) ? cnt1 : CAND_CAP;
    u64 c = (lane < m1) ? cand[w2 + 1][lane] : ~0ull;
    u64 d = (lane + 64 < m1) ? cand[w2 + 1][lane + 64] : ~0ull;
    u64 j0 = (c < d) ? c : d, j1 = (c < d) ? d : c;
#pragma unroll
    for (int r = 0; r < KNN; ++r) {
      u64 mm = wave_min_u64(j0);
      ni1_[r] = (int)(unsigned)(mm & 0xFFFFFFFFu);
      if (j0 == mm) { j0 = j1; j1 = ~0ull; }
    }
  }

  // ---- attention (order-invariant). agg aliases q: each wave writes only
  // its own 2 rows, after reading its own q rows. ----
  const float lg = *log_gamma_p;
  attend_one(c4, q, k, v, lg, base, n0, qp0, ni0_, lane, agg);
  attend_one(c4, q, k, v, lg, base, n0 + 1, qp1, ni1_, lane, agg);
}

// ---------------------------------------------------------------------------
extern "C" void kernel_launch(void* const* d_in, const int* in_sizes, int n_in,
                              void* d_out, int out_size, void* d_ws, size_t ws_size,
                              hipStream_t stream) {
  const float* feats  = (const float*)d_in[0];
  const float* coords = (const float*)d_in[1];
  const float* Wq     = (const float*)d_in[2];
  const float* Wk     = (const float*)d_in[3];
  const float* Wv     = (const float*)d_in[4];
  const float* Wo     = (const float*)d_in[5];
  const float* lg     = (const float*)d_in[6];
  float* out = (float*)d_out;

  float* ws = (float*)d_ws;
  const size_t ROWS = (size_t)M_TOTAL * C_DIM;   // 2,097,152 floats
  float*  q   = ws;                               // 8 MB
  float*  k   = ws + ROWS;                        // 8 MB
  float*  v   = ws + 2 * ROWS;                    // 8 MB
  float4* c4  = (float4*)(ws + 3 * ROWS);         // 256 KB, 16B-aligned
  float*  WTq = ws + 3 * ROWS + 4 * (size_t)M_TOTAL;
  float*  WTk = WTq + C_DIM * C_DIM;
  float*  WTv = WTk + C_DIM * C_DIM;
  float*  WTo = WTv + C_DIM * C_DIM;              // total ws use: ~24.8 MB
  float*  agg = q;                                // reuse q's buffer

  prep_coords<<<M_TOTAL / 256, 256, 0, stream>>>(coords, c4);
  transpose_w<<<256, 256, 0, stream>>>(Wq, Wk, Wv, Wo, WTq, WTk, WTv, WTo);
  gemm_qkv<<<M_TOTAL / 32, 256, 0, stream>>>(feats, WTq, WTk, WTv, q, k, v);
  knn_attn<<<M_TOTAL / 8, 256, 0, stream>>>(c4, q, k, v, lg, agg);
  gemm_xwt<<<M_TOTAL / 32, 256, 0, stream>>>(agg, WTo, out);
}

// Round 11
// 218.734 us; speedup vs baseline: 1.1193x; 1.1193x over previous
//
#include <hip/hip_runtime.h>
#include <math.h>

#define C_DIM 128
#define KNN 8
#define NPTS 8192
#define M_TOTAL 16384   // B*N
#define CHUNK 1024      // points staged in LDS per iteration of the KNN scan
#define CAND_CAP 64     // per-query candidate buffer (expected use: 10-16)

typedef unsigned long long u64;

// ---------------------------------------------------------------------------
// Kernel 1: coords -> packed float4 {x, y, z, |p|^2} per point
// ---------------------------------------------------------------------------
__global__ __launch_bounds__(256) void prep_coords(
    const float* __restrict__ coords, float4* __restrict__ c4) {
  int g = blockIdx.x * 256 + threadIdx.x;
  if (g < M_TOTAL) {
    float x = coords[3 * g + 0];
    float y = coords[3 * g + 1];
    float z = coords[3 * g + 2];
    // same fma ordering as the scan's dot product so self-distance cancels
    // to exactly 0.0f
    float s = fmaf(x, x, fmaf(y, y, z * z));
    c4[g] = make_float4(x, y, z, s);
  }
}

// ---------------------------------------------------------------------------
// Kernel 2: transpose the four 128x128 weight matrices once: WT[c][o]=W[o][c]
// ---------------------------------------------------------------------------
__global__ __launch_bounds__(256) void transpose_w(
    const float* __restrict__ Wq, const float* __restrict__ Wk,
    const float* __restrict__ Wv, const float* __restrict__ Wo,
    float* __restrict__ Tq, float* __restrict__ Tk,
    float* __restrict__ Tv, float* __restrict__ To) {
  int g = blockIdx.x * 256 + threadIdx.x;
  int mat = g >> 14;          // 0..3
  int j = g & 16383;          // dest linear index: j = c*128 + o
  int c = j >> 7, o = j & 127;
  const float* src = (mat == 0) ? Wq : (mat == 1) ? Wk : (mat == 2) ? Wv : Wo;
  float* dst = (mat == 0) ? Tq : (mat == 1) ? Tk : (mat == 2) ? Tv : To;
  dst[j] = src[o * C_DIM + c];   // coalesced write, strided (L2-hit) read
}

// ---------------------------------------------------------------------------
__device__ __forceinline__ void stage_x64(
    float (*Xs)[132], const float* __restrict__ X, int row0, int t) {
  const float4* X4 = (const float4*)(X + (size_t)row0 * C_DIM);
  for (int i = t; i < 64 * 32; i += 256) {
    int r = i >> 5, c4i = i & 31;
    *(float4*)&Xs[r][c4i * 4] = X4[i];
  }
}

// ---------------------------------------------------------------------------
// Kernel 3a: fused q/k/v projection, split-N: 512 blocks of 64 rows x 64
// cols (2 blocks/CU -> latency hiding), 4x4x3 per thread. Measured best
// (R10: non-knn 110 -> 97us). Per-output FMA order unchanged.
// ---------------------------------------------------------------------------
__global__ __launch_bounds__(256) void gemm_qkv(
    const float* __restrict__ X,
    const float* __restrict__ WTq, const float* __restrict__ WTk,
    const float* __restrict__ WTv,
    float* __restrict__ Yq, float* __restrict__ Yk, float* __restrict__ Yv) {
  __shared__ float Xs[64][132];
  const int t = threadIdx.x;
  const int row0 = (blockIdx.x >> 1) * 64;
  const int ob = (blockIdx.x & 1) * 64;   // which 64-col half
  stage_x64(Xs, X, row0, t);
  __syncthreads();

  const int r0 = (t >> 4) * 4;
  const int o0 = ob + (t & 15) * 4;

  float aq[4][4], ak[4][4], av[4][4];
#pragma unroll
  for (int i = 0; i < 4; ++i)
#pragma unroll
    for (int j = 0; j < 4; ++j) { aq[i][j] = 0.f; ak[i][j] = 0.f; av[i][j] = 0.f; }

  for (int c = 0; c < C_DIM; c += 4) {
    float xs[4][4];
#pragma unroll
    for (int i = 0; i < 4; ++i) {
      float4 xv = *(const float4*)&Xs[r0 + i][c];
      xs[i][0] = xv.x; xs[i][1] = xv.y; xs[i][2] = xv.z; xs[i][3] = xv.w;
    }
#pragma unroll
    for (int cc = 0; cc < 4; ++cc) {
      const size_t wrow = (size_t)(c + cc) * C_DIM + o0;
      float4 qa = *(const float4*)&WTq[wrow];
      float4 ka = *(const float4*)&WTk[wrow];
      float4 va = *(const float4*)&WTv[wrow];
#pragma unroll
      for (int i = 0; i < 4; ++i) {
        float x = xs[i][cc];
        aq[i][0] = fmaf(x, qa.x, aq[i][0]); aq[i][1] = fmaf(x, qa.y, aq[i][1]);
        aq[i][2] = fmaf(x, qa.z, aq[i][2]); aq[i][3] = fmaf(x, qa.w, aq[i][3]);
        ak[i][0] = fmaf(x, ka.x, ak[i][0]); ak[i][1] = fmaf(x, ka.y, ak[i][1]);
        ak[i][2] = fmaf(x, ka.z, ak[i][2]); ak[i][3] = fmaf(x, ka.w, ak[i][3]);
        av[i][0] = fmaf(x, va.x, av[i][0]); av[i][1] = fmaf(x, va.y, av[i][1]);
        av[i][2] = fmaf(x, va.z, av[i][2]); av[i][3] = fmaf(x, va.w, av[i][3]);
      }
    }
  }

#pragma unroll
  for (int i = 0; i < 4; ++i) {
    const size_t yoff = (size_t)(row0 + r0 + i) * C_DIM + o0;
    *(float4*)&Yq[yoff] = make_float4(aq[i][0], aq[i][1], aq[i][2], aq[i][3]);
    *(float4*)&Yk[yoff] = make_float4(ak[i][0], ak[i][1], ak[i][2], ak[i][3]);
    *(float4*)&Yv[yoff] = make_float4(av[i][0], av[i][1], av[i][2], av[i][3]);
  }
}

// ---------------------------------------------------------------------------
// Kernel 3b: output projection, same split-N scheme (512 blocks).
// ---------------------------------------------------------------------------
__global__ __launch_bounds__(256) void gemm_xwt(
    const float* __restrict__ X, const float* __restrict__ WT,
    float* __restrict__ Y) {
  __shared__ float Xs[64][132];
  const int t = threadIdx.x;
  const int row0 = (blockIdx.x >> 1) * 64;
  const int ob = (blockIdx.x & 1) * 64;
  stage_x64(Xs, X, row0, t);
  __syncthreads();

  const int r0 = (t >> 4) * 4;
  const int o0 = ob + (t & 15) * 4;

  float acc[4][4];
#pragma unroll
  for (int i = 0; i < 4; ++i)
#pragma unroll
    for (int j = 0; j < 4; ++j) acc[i][j] = 0.0f;

  for (int c = 0; c < C_DIM; c += 4) {
    float xs[4][4];
#pragma unroll
    for (int i = 0; i < 4; ++i) {
      float4 xv = *(const float4*)&Xs[r0 + i][c];
      xs[i][0] = xv.x; xs[i][1] = xv.y; xs[i][2] = xv.z; xs[i][3] = xv.w;
    }
#pragma unroll
    for (int cc = 0; cc < 4; ++cc) {
      const size_t wrow = (size_t)(c + cc) * C_DIM + o0;
      float4 wa = *(const float4*)&WT[wrow];
#pragma unroll
      for (int i = 0; i < 4; ++i) {
        float x = xs[i][cc];
        acc[i][0] = fmaf(x, wa.x, acc[i][0]); acc[i][1] = fmaf(x, wa.y, acc[i][1]);
        acc[i][2] = fmaf(x, wa.z, acc[i][2]); acc[i][3] = fmaf(x, wa.w, acc[i][3]);
      }
    }
  }

#pragma unroll
  for (int i = 0; i < 4; ++i) {
    float* yrow = Y + (size_t)(row0 + r0 + i) * C_DIM + o0;
    *(float4*)yrow = make_float4(acc[i][0], acc[i][1], acc[i][2], acc[i][3]);
  }
}

// ---------------------------------------------------------------------------
// Kernel 4: fused KNN + attention, ONE query/wave (low VGPR -> occupancy),
// cheap top-2 pass A (R9's win), full-scan tau (tight: in [s8, ~s12]),
// ballot-compact pass B, exact lex-(d2,idx) final select.
// R10's chunk-0-only tau + per-chunk tightening REVERTED: the tau_from_cands
// machinery cost ~2K instrs + LDS bank conflicts and made tau looser (148us
// vs R9's 120). R8 showed 2-queries/wave is time-neutral but +28 VGPR
// (occupancy 63% -> 40%), so back to 1 query/wave.
// ---------------------------------------------------------------------------
__device__ __forceinline__ u64 wave_min_u64(u64 x) {
#pragma unroll
  for (int off = 32; off > 0; off >>= 1) {
    u64 o = __shfl_xor(x, off, 64);
    x = (o < x) ? o : x;
  }
  return x;
}

// wave 8th-smallest over per-lane ascending pairs (u0 <= u1)
__device__ __forceinline__ float wave_8th_of_top2(float u0, float u1) {
  float m = 0.0f;
#pragma unroll
  for (int r = 0; r < KNN; ++r) {
    m = u0;
#pragma unroll
    for (int off = 32; off > 0; off >>= 1) {
      float o = __shfl_xor(m, off, 64);
      m = fminf(m, o);
    }
    bool mine = (u0 == m);   // every lane holding m pops one element
    u0 = mine ? u1 : u0;
    u1 = mine ? INFINITY : u1;
  }
  return m;
}

__global__ __launch_bounds__(256) void knn_attn(
    const float4* __restrict__ c4,
    const float* __restrict__ q, const float* __restrict__ k,
    const float* __restrict__ v, const float* __restrict__ log_gamma_p,
    float* __restrict__ agg) {
  __shared__ float4 pts[CHUNK];          // 16 KB
  __shared__ u64 cand[4][CAND_CAP];      // 2 KB, per-query candidate buffers

  const int t = threadIdx.x;
  const int wave = t >> 6;
  const int lane = t & 63;
  const int qi = blockIdx.x * 4 + wave;          // blocks never straddle batch
  const int b = qi >> 13;
  const int n = qi & (NPTS - 1);
  const int base = b * NPTS;

  const float4 qp = c4[base + n];   // {x,y,z,|p|^2}
  const u64 lmask = (1ull << lane) - 1ull;

  // ---------------- pass A: per-lane top-2 only, branchless ---------------
  float m1 = INFINITY, m2 = INFINITY;

  for (int ch = 0; ch < NPTS / CHUNK; ++ch) {
    __syncthreads();   // previous chunk fully consumed
    for (int i = t; i < CHUNK; i += 256) pts[i] = c4[base + ch * CHUNK + i];
    __syncthreads();

#pragma unroll
    for (int it = 0; it < CHUNK / 128; ++it) {   // 2 points per lane per iter
      const int ml = it * 128 + lane;
      const float4 pa = pts[ml];
      const float4 pb = pts[ml + 64];
      float dota = fmaf(qp.x, pa.x, fmaf(qp.y, pa.y, qp.z * pa.z));
      float dotb = fmaf(qp.x, pb.x, fmaf(qp.y, pb.y, qp.z * pb.z));
      float d2a = fmaxf(qp.w + pa.w - 2.0f * dota, 0.0f);
      float d2b = fmaxf(qp.w + pb.w - 2.0f * dotb, 0.0f);
      // top-2 update: 3 ops per point
      float h;
      h = fmaxf(m1, d2a); m1 = fminf(m1, d2a); m2 = fminf(m2, h);
      h = fmaxf(m1, d2b); m1 = fminf(m1, d2b); m2 = fminf(m2, h);
    }
  }

  // tau >= s8 (subset order statistic over 128 retained values); tau <= ~s12
  const float tau = wave_8th_of_top2(m1, m2);

  // ---------------- pass B: collect candidates <= tau ---------------------
  int cnt = 0;
  for (int ch = 0; ch < NPTS / CHUNK; ++ch) {
    __syncthreads();
    for (int i = t; i < CHUNK; i += 256) pts[i] = c4[base + ch * CHUNK + i];
    __syncthreads();

#pragma unroll
    for (int it = 0; it < CHUNK / 128; ++it) {
      const int ml = it * 128 + lane;
      const float4 pa = pts[ml];
      const float4 pb = pts[ml + 64];
      float dota = fmaf(qp.x, pa.x, fmaf(qp.y, pa.y, qp.z * pa.z));
      float dotb = fmaf(qp.x, pb.x, fmaf(qp.y, pb.y, qp.z * pb.z));
      float d2a = fmaxf(qp.w + pa.w - 2.0f * dota, 0.0f);
      float d2b = fmaxf(qp.w + pb.w - 2.0f * dotb, 0.0f);
      bool ga = d2a <= tau;
      bool gb = d2b <= tau;
      u64 mska = __ballot(ga);
      u64 mskb = __ballot(gb);
      if (mska | mskb) {   // rarely-taken, wave-uniform branch
        const unsigned ia = (unsigned)(ch * CHUNK + ml);
        if (ga) {
          int pos = cnt + (int)__popcll(mska & lmask);
          if (pos < CAND_CAP)
            cand[wave][pos] = ((u64)__float_as_uint(d2a) << 32) | ia;
        }
        cnt += (int)__popcll(mska);
        if (gb) {
          int pos = cnt + (int)__popcll(mskb & lmask);
          if (pos < CAND_CAP)
            cand[wave][pos] = ((u64)__float_as_uint(d2b) << 32) | (ia + 64);
        }
        cnt += (int)__popcll(mskb);
      }
    }
  }

  // ------------- final exact top-8 over candidates (lex (d2, idx)) -------
  const int m_ = (cnt < CAND_CAP) ? cnt : CAND_CAP;
  u64 mykey = (lane < m_) ? cand[wave][lane] : ~0ull;
  int ni_[KNN];
#pragma unroll
  for (int r = 0; r < KNN; ++r) {
    u64 mm = wave_min_u64(mykey);
    ni_[r] = (int)(unsigned)(mm & 0xFFFFFFFFu);
    if (mykey == mm) mykey = ~0ull;   // keys unique: single owner pops
  }

  // ---- attention over the 8 neighbors (output is order-invariant) ----
  const float lg = *log_gamma_p;
  const size_t qrow = (size_t)(base + n) * C_DIM;
  const float qv0 = q[qrow + lane];
  const float qv1 = q[qrow + lane + 64];

  float score[KNN];
#pragma unroll
  for (int j = 0; j < KNN; ++j) {
    const int mj = ni_[j];
    const size_t krow = (size_t)(base + mj) * C_DIM;
    float p = fmaf(qv1, k[krow + lane + 64], qv0 * k[krow + lane]);
#pragma unroll
    for (int off = 32; off > 0; off >>= 1) p += __shfl_xor(p, off, 64);
    // gamma from the diff-based safe norm (reference's second formula)
    const float4 pm = c4[base + mj];
    float dx = qp.x - pm.x, dy = qp.y - pm.y, dz = qp.z - pm.z;
    float d2p = fmaf(dx, dx, fmaf(dy, dy, dz * dz));
    float dist = d2p > 0.0f ? sqrtf(d2p) : 0.0f;
    float gw = expf(lg * dist);
    score[j] = (p / 11.313708498984761f) * gw;   // /sqrt(128) then *gamma
  }

  float mx = score[0];
#pragma unroll
  for (int j = 1; j < KNN; ++j) mx = fmaxf(mx, score[j]);
  float w[KNN]; float sum = 0.0f;
#pragma unroll
  for (int j = 0; j < KNN; ++j) { w[j] = expf(score[j] - mx); sum += w[j]; }
#pragma unroll
  for (int j = 0; j < KNN; ++j) w[j] = w[j] / sum;

  float a0 = 0.0f, a1 = 0.0f;
#pragma unroll
  for (int j = 0; j < KNN; ++j) {
    const size_t vrow = (size_t)(base + ni_[j]) * C_DIM;
    a0 = fmaf(w[j], v[vrow + lane], a0);
    a1 = fmaf(w[j], v[vrow + lane + 64], a1);
  }
  // agg aliases q's storage: safe, each q row is read only by its own wave
  agg[qrow + lane] = a0;
  agg[qrow + lane + 64] = a1;
}

// ---------------------------------------------------------------------------
extern "C" void kernel_launch(void* const* d_in, const int* in_sizes, int n_in,
                              void* d_out, int out_size, void* d_ws, size_t ws_size,
                              hipStream_t stream) {
  const float* feats  = (const float*)d_in[0];
  const float* coords = (const float*)d_in[1];
  const float* Wq     = (const float*)d_in[2];
  const float* Wk     = (const float*)d_in[3];
  const float* Wv     = (const float*)d_in[4];
  const float* Wo     = (const float*)d_in[5];
  const float* lg     = (const float*)d_in[6];
  float* out = (float*)d_out;

  float* ws = (float*)d_ws;
  const size_t ROWS = (size_t)M_TOTAL * C_DIM;   // 2,097,152 floats
  float*  q   = ws;                               // 8 MB
  float*  k   = ws + ROWS;                        // 8 MB
  float*  v   = ws + 2 * ROWS;                    // 8 MB
  float4* c4  = (float4*)(ws + 3 * ROWS);         // 256 KB, 16B-aligned
  float*  WTq = ws + 3 * ROWS + 4 * (size_t)M_TOTAL;
  float*  WTk = WTq + C_DIM * C_DIM;
  float*  WTv = WTk + C_DIM * C_DIM;
  float*  WTo = WTv + C_DIM * C_DIM;              // total ws use: ~24.8 MB
  float*  agg = q;                                // reuse q's buffer

  prep_coords<<<M_TOTAL / 256, 256, 0, stream>>>(coords, c4);
  transpose_w<<<256, 256, 0, stream>>>(Wq, Wk, Wv, Wo, WTq, WTk, WTv, WTo);
  gemm_qkv<<<M_TOTAL / 32, 256, 0, stream>>>(feats, WTq, WTk, WTv, q, k, v);
  knn_attn<<<M_TOTAL / 4, 256, 0, stream>>>(c4, q, k, v, lg, agg);
  gemm_xwt<<<M_TOTAL / 32, 256, 0, stream>>>(agg, WTo, out);
}

// Round 12
// 196.434 us; speedup vs baseline: 1.2464x; 1.1135x over previous
//
#include <hip/hip_runtime.h>
#include <math.h>

#define C_DIM 128
#define KNN 8
#define NPTS 8192
#define M_TOTAL 16384   // B*N
#define CHUNK 1024      // points staged in LDS per iteration of the KNN scan
#define SAMPLE 2048     // pass-A sample size (global reads, L1-resident)
#define CAND_CAP 96     // per-query candidate buffer (expected use ~34)

typedef unsigned long long u64;

// ---------------------------------------------------------------------------
// Kernel 1: coords -> packed float4 {x, y, z, |p|^2} per point
// ---------------------------------------------------------------------------
__global__ __launch_bounds__(256) void prep_coords(
    const float* __restrict__ coords, float4* __restrict__ c4) {
  int g = blockIdx.x * 256 + threadIdx.x;
  if (g < M_TOTAL) {
    float x = coords[3 * g + 0];
    float y = coords[3 * g + 1];
    float z = coords[3 * g + 2];
    // same fma ordering as the scan's dot product so self-distance cancels
    // to exactly 0.0f
    float s = fmaf(x, x, fmaf(y, y, z * z));
    c4[g] = make_float4(x, y, z, s);
  }
}

// ---------------------------------------------------------------------------
// Kernel 2: transpose the four 128x128 weight matrices once: WT[c][o]=W[o][c]
// ---------------------------------------------------------------------------
__global__ __launch_bounds__(256) void transpose_w(
    const float* __restrict__ Wq, const float* __restrict__ Wk,
    const float* __restrict__ Wv, const float* __restrict__ Wo,
    float* __restrict__ Tq, float* __restrict__ Tk,
    float* __restrict__ Tv, float* __restrict__ To) {
  int g = blockIdx.x * 256 + threadIdx.x;
  int mat = g >> 14;          // 0..3
  int j = g & 16383;          // dest linear index: j = c*128 + o
  int c = j >> 7, o = j & 127;
  const float* src = (mat == 0) ? Wq : (mat == 1) ? Wk : (mat == 2) ? Wv : Wo;
  float* dst = (mat == 0) ? Tq : (mat == 1) ? Tk : (mat == 2) ? Tv : To;
  dst[j] = src[o * C_DIM + c];   // coalesced write, strided (L2-hit) read
}

// ---------------------------------------------------------------------------
__device__ __forceinline__ void stage_x64(
    float (*Xs)[132], const float* __restrict__ X, int row0, int t) {
  const float4* X4 = (const float4*)(X + (size_t)row0 * C_DIM);
  for (int i = t; i < 64 * 32; i += 256) {
    int r = i >> 5, c4i = i & 31;
    *(float4*)&Xs[r][c4i * 4] = X4[i];
  }
}

// ---------------------------------------------------------------------------
// Kernel 3a: fused q/k/v projection, split-N: 512... 1024 blocks of 64 rows
// x 64 cols (latency hiding), 4x4x3 per thread. Measured best (R10/R11:
// non-knn ~95-97us). Per-output FMA order unchanged.
// ---------------------------------------------------------------------------
__global__ __launch_bounds__(256) void gemm_qkv(
    const float* __restrict__ X,
    const float* __restrict__ WTq, const float* __restrict__ WTk,
    const float* __restrict__ WTv,
    float* __restrict__ Yq, float* __restrict__ Yk, float* __restrict__ Yv) {
  __shared__ float Xs[64][132];
  const int t = threadIdx.x;
  const int row0 = (blockIdx.x >> 1) * 64;
  const int ob = (blockIdx.x & 1) * 64;   // which 64-col half
  stage_x64(Xs, X, row0, t);
  __syncthreads();

  const int r0 = (t >> 4) * 4;
  const int o0 = ob + (t & 15) * 4;

  float aq[4][4], ak[4][4], av[4][4];
#pragma unroll
  for (int i = 0; i < 4; ++i)
#pragma unroll
    for (int j = 0; j < 4; ++j) { aq[i][j] = 0.f; ak[i][j] = 0.f; av[i][j] = 0.f; }

  for (int c = 0; c < C_DIM; c += 4) {
    float xs[4][4];
#pragma unroll
    for (int i = 0; i < 4; ++i) {
      float4 xv = *(const float4*)&Xs[r0 + i][c];
      xs[i][0] = xv.x; xs[i][1] = xv.y; xs[i][2] = xv.z; xs[i][3] = xv.w;
    }
#pragma unroll
    for (int cc = 0; cc < 4; ++cc) {
      const size_t wrow = (size_t)(c + cc) * C_DIM + o0;
      float4 qa = *(const float4*)&WTq[wrow];
      float4 ka = *(const float4*)&WTk[wrow];
      float4 va = *(const float4*)&WTv[wrow];
#pragma unroll
      for (int i = 0; i < 4; ++i) {
        float x = xs[i][cc];
        aq[i][0] = fmaf(x, qa.x, aq[i][0]); aq[i][1] = fmaf(x, qa.y, aq[i][1]);
        aq[i][2] = fmaf(x, qa.z, aq[i][2]); aq[i][3] = fmaf(x, qa.w, aq[i][3]);
        ak[i][0] = fmaf(x, ka.x, ak[i][0]); ak[i][1] = fmaf(x, ka.y, ak[i][1]);
        ak[i][2] = fmaf(x, ka.z, ak[i][2]); ak[i][3] = fmaf(x, ka.w, ak[i][3]);
        av[i][0] = fmaf(x, va.x, av[i][0]); av[i][1] = fmaf(x, va.y, av[i][1]);
        av[i][2] = fmaf(x, va.z, av[i][2]); av[i][3] = fmaf(x, va.w, av[i][3]);
      }
    }
  }

#pragma unroll
  for (int i = 0; i < 4; ++i) {
    const size_t yoff = (size_t)(row0 + r0 + i) * C_DIM + o0;
    *(float4*)&Yq[yoff] = make_float4(aq[i][0], aq[i][1], aq[i][2], aq[i][3]);
    *(float4*)&Yk[yoff] = make_float4(ak[i][0], ak[i][1], ak[i][2], ak[i][3]);
    *(float4*)&Yv[yoff] = make_float4(av[i][0], av[i][1], av[i][2], av[i][3]);
  }
}

// ---------------------------------------------------------------------------
// Kernel 3b: output projection, same split-N scheme (1024 blocks).
// ---------------------------------------------------------------------------
__global__ __launch_bounds__(256) void gemm_xwt(
    const float* __restrict__ X, const float* __restrict__ WT,
    float* __restrict__ Y) {
  __shared__ float Xs[64][132];
  const int t = threadIdx.x;
  const int row0 = (blockIdx.x >> 1) * 64;
  const int ob = (blockIdx.x & 1) * 64;
  stage_x64(Xs, X, row0, t);
  __syncthreads();

  const int r0 = (t >> 4) * 4;
  const int o0 = ob + (t & 15) * 4;

  float acc[4][4];
#pragma unroll
  for (int i = 0; i < 4; ++i)
#pragma unroll
    for (int j = 0; j < 4; ++j) acc[i][j] = 0.0f;

  for (int c = 0; c < C_DIM; c += 4) {
    float xs[4][4];
#pragma unroll
    for (int i = 0; i < 4; ++i) {
      float4 xv = *(const float4*)&Xs[r0 + i][c];
      xs[i][0] = xv.x; xs[i][1] = xv.y; xs[i][2] = xv.z; xs[i][3] = xv.w;
    }
#pragma unroll
    for (int cc = 0; cc < 4; ++cc) {
      const size_t wrow = (size_t)(c + cc) * C_DIM + o0;
      float4 wa = *(const float4*)&WT[wrow];
#pragma unroll
      for (int i = 0; i < 4; ++i) {
        float x = xs[i][cc];
        acc[i][0] = fmaf(x, wa.x, acc[i][0]); acc[i][1] = fmaf(x, wa.y, acc[i][1]);
        acc[i][2] = fmaf(x, wa.z, acc[i][2]); acc[i][3] = fmaf(x, wa.w, acc[i][3]);
      }
    }
  }

#pragma unroll
  for (int i = 0; i < 4; ++i) {
    float* yrow = Y + (size_t)(row0 + r0 + i) * C_DIM + o0;
    *(float4*)yrow = make_float4(acc[i][0], acc[i][1], acc[i][2], acc[i][3]);
  }
}

// ---------------------------------------------------------------------------
// Kernel 4: fused KNN + attention, 1 query/wave, SAMPLED-tau pass A.
// Pass A: top-2/lane over the FIRST 2048 points only, read directly from
//   global (32 coalesced b128 loads; region is L1-resident since all blocks
//   read it). tau = wave 8th of the 128 retained values. Subset order
//   statistic: tau >= s8(sample) >= s8(all) -> filter is exact-safe.
//   No LDS staging, no barriers in pass A (halves LDS traffic + barriers).
// Pass B: LDS-chunked full scan; d2 <= tau -> ballot-compact (d2,idx);
//   E[cands] ~ 34, CAP 96 (overflow P ~ 1e-13). Final: exact lex-(d2,idx)
//   butterfly-min-pop, 2 keys/lane (handles up to 128 candidates).
// ---------------------------------------------------------------------------
__device__ __forceinline__ u64 wave_min_u64(u64 x) {
#pragma unroll
  for (int off = 32; off > 0; off >>= 1) {
    u64 o = __shfl_xor(x, off, 64);
    x = (o < x) ? o : x;
  }
  return x;
}

// wave 8th-smallest over per-lane ascending pairs (u0 <= u1)
__device__ __forceinline__ float wave_8th_of_top2(float u0, float u1) {
  float m = 0.0f;
#pragma unroll
  for (int r = 0; r < KNN; ++r) {
    m = u0;
#pragma unroll
    for (int off = 32; off > 0; off >>= 1) {
      float o = __shfl_xor(m, off, 64);
      m = fminf(m, o);
    }
    bool mine = (u0 == m);   // every lane holding m pops one element
    u0 = mine ? u1 : u0;
    u1 = mine ? INFINITY : u1;
  }
  return m;
}

__global__ __launch_bounds__(256) void knn_attn(
    const float4* __restrict__ c4,
    const float* __restrict__ q, const float* __restrict__ k,
    const float* __restrict__ v, const float* __restrict__ log_gamma_p,
    float* __restrict__ agg) {
  __shared__ float4 pts[CHUNK];          // 16 KB
  __shared__ u64 cand[4][CAND_CAP];      // 3 KB, per-query candidate buffers

  const int t = threadIdx.x;
  const int wave = t >> 6;
  const int lane = t & 63;
  const int qi = blockIdx.x * 4 + wave;          // blocks never straddle batch
  const int b = qi >> 13;
  const int n = qi & (NPTS - 1);
  const int base = b * NPTS;

  const float4 qp = c4[base + n];   // {x,y,z,|p|^2}
  const u64 lmask = (1ull << lane) - 1ull;

  // ------- pass A: sampled tau (first SAMPLE points, global reads) --------
  float m1 = INFINITY, m2 = INFINITY;
  const float4* cb = c4 + base;
#pragma unroll 4
  for (int it = 0; it < SAMPLE / 64; ++it) {
    const float4 p = cb[it * 64 + lane];
    float dot = fmaf(qp.x, p.x, fmaf(qp.y, p.y, qp.z * p.z));
    float d2 = fmaxf(qp.w + p.w - 2.0f * dot, 0.0f);
    float h = fmaxf(m1, d2); m1 = fminf(m1, d2); m2 = fminf(m2, h);
  }
  // tau >= s8(sample) >= s8(all): exact-safe filter threshold
  const float tau = wave_8th_of_top2(m1, m2);

  // ---------------- pass B: collect candidates <= tau ---------------------
  int cnt = 0;
  for (int ch = 0; ch < NPTS / CHUNK; ++ch) {
    __syncthreads();
    for (int i = t; i < CHUNK; i += 256) pts[i] = c4[base + ch * CHUNK + i];
    __syncthreads();

#pragma unroll
    for (int it = 0; it < CHUNK / 128; ++it) {
      const int ml = it * 128 + lane;
      const float4 pa = pts[ml];
      const float4 pb = pts[ml + 64];
      float dota = fmaf(qp.x, pa.x, fmaf(qp.y, pa.y, qp.z * pa.z));
      float dotb = fmaf(qp.x, pb.x, fmaf(qp.y, pb.y, qp.z * pb.z));
      float d2a = fmaxf(qp.w + pa.w - 2.0f * dota, 0.0f);
      float d2b = fmaxf(qp.w + pb.w - 2.0f * dotb, 0.0f);
      bool ga = d2a <= tau;
      bool gb = d2b <= tau;
      u64 mska = __ballot(ga);
      u64 mskb = __ballot(gb);
      if (mska | mskb) {   // rarely-taken, wave-uniform branch
        const unsigned ia = (unsigned)(ch * CHUNK + ml);
        if (ga) {
          int pos = cnt + (int)__popcll(mska & lmask);
          if (pos < CAND_CAP)
            cand[wave][pos] = ((u64)__float_as_uint(d2a) << 32) | ia;
        }
        cnt += (int)__popcll(mska);
        if (gb) {
          int pos = cnt + (int)__popcll(mskb & lmask);
          if (pos < CAND_CAP)
            cand[wave][pos] = ((u64)__float_as_uint(d2b) << 32) | (ia + 64);
        }
        cnt += (int)__popcll(mskb);
      }
    }
  }

  // ------- final exact top-8 over candidates (lex (d2, idx)), 2 keys/lane -
  const int m_ = (cnt < CAND_CAP) ? cnt : CAND_CAP;
  u64 a = (lane < m_) ? cand[wave][lane] : ~0ull;
  u64 bb = (lane + 64 < m_) ? cand[wave][lane + 64] : ~0ull;
  u64 k0 = (a < bb) ? a : bb, k1 = (a < bb) ? bb : a;
  int ni_[KNN];
#pragma unroll
  for (int r = 0; r < KNN; ++r) {
    u64 mm = wave_min_u64(k0);
    ni_[r] = (int)(unsigned)(mm & 0xFFFFFFFFu);
    if (k0 == mm) { k0 = k1; k1 = ~0ull; }   // keys unique: owner pops
  }

  // ---- attention over the 8 neighbors (output is order-invariant) ----
  const float lg = *log_gamma_p;
  const size_t qrow = (size_t)(base + n) * C_DIM;
  const float qv0 = q[qrow + lane];
  const float qv1 = q[qrow + lane + 64];

  float score[KNN];
#pragma unroll
  for (int j = 0; j < KNN; ++j) {
    const int mj = ni_[j];
    const size_t krow = (size_t)(base + mj) * C_DIM;
    float p = fmaf(qv1, k[krow + lane + 64], qv0 * k[krow + lane]);
#pragma unroll
    for (int off = 32; off > 0; off >>= 1) p += __shfl_xor(p, off, 64);
    // gamma from the diff-based safe norm (reference's second formula)
    const float4 pm = c4[base + mj];
    float dx = qp.x - pm.x, dy = qp.y - pm.y, dz = qp.z - pm.z;
    float d2p = fmaf(dx, dx, fmaf(dy, dy, dz * dz));
    float dist = d2p > 0.0f ? sqrtf(d2p) : 0.0f;
    float gw = expf(lg * dist);
    score[j] = (p / 11.313708498984761f) * gw;   // /sqrt(128) then *gamma
  }

  float mx = score[0];
#pragma unroll
  for (int j = 1; j < KNN; ++j) mx = fmaxf(mx, score[j]);
  float w[KNN]; float sum = 0.0f;
#pragma unroll
  for (int j = 0; j < KNN; ++j) { w[j] = expf(score[j] - mx); sum += w[j]; }
#pragma unroll
  for (int j = 0; j < KNN; ++j) w[j] = w[j] / sum;

  float a0 = 0.0f, a1 = 0.0f;
#pragma unroll
  for (int j = 0; j < KNN; ++j) {
    const size_t vrow = (size_t)(base + ni_[j]) * C_DIM;
    a0 = fmaf(w[j], v[vrow + lane], a0);
    a1 = fmaf(w[j], v[vrow + lane + 64], a1);
  }
  // agg aliases q's storage: safe, each q row is read only by its own wave
  agg[qrow + lane] = a0;
  agg[qrow + lane + 64] = a1;
}

// ---------------------------------------------------------------------------
extern "C" void kernel_launch(void* const* d_in, const int* in_sizes, int n_in,
                              void* d_out, int out_size, void* d_ws, size_t ws_size,
                              hipStream_t stream) {
  const float* feats  = (const float*)d_in[0];
  const float* coords = (const float*)d_in[1];
  const float* Wq     = (const float*)d_in[2];
  const float* Wk     = (const float*)d_in[3];
  const float* Wv     = (const float*)d_in[4];
  const float* Wo     = (const float*)d_in[5];
  const float* lg     = (const float*)d_in[6];
  float* out = (float*)d_out;

  float* ws = (float*)d_ws;
  const size_t ROWS = (size_t)M_TOTAL * C_DIM;   // 2,097,152 floats
  float*  q   = ws;                               // 8 MB
  float*  k   = ws + ROWS;                        // 8 MB
  float*  v   = ws + 2 * ROWS;                    // 8 MB
  float4* c4  = (float4*)(ws + 3 * ROWS);         // 256 KB, 16B-aligned
  float*  WTq = ws + 3 * ROWS + 4 * (size_t)M_TOTAL;
  float*  WTk = WTq + C_DIM * C_DIM;
  float*  WTv = WTk + C_DIM * C_DIM;
  float*  WTo = WTv + C_DIM * C_DIM;              // total ws use: ~24.8 MB
  float*  agg = q;                                // reuse q's buffer

  prep_coords<<<M_TOTAL / 256, 256, 0, stream>>>(coords, c4);
  transpose_w<<<256, 256, 0, stream>>>(Wq, Wk, Wv, Wo, WTq, WTk, WTv, WTo);
  gemm_qkv<<<M_TOTAL / 32, 256, 0, stream>>>(feats, WTq, WTk, WTv, q, k, v);
  knn_attn<<<M_TOTAL / 4, 256, 0, stream>>>(c4, q, k, v, lg, agg);
  gemm_xwt<<<M_TOTAL / 32, 256, 0, stream>>>(agg, WTo, out);
}

// Round 13
// 193.559 us; speedup vs baseline: 1.2649x; 1.0149x over previous
//
#include <hip/hip_runtime.h>
#include <math.h>

#define C_DIM 128
#define KNN 8
#define NPTS 8192
#define M_TOTAL 16384   // B*N
#define CHUNK 1024      // points staged in LDS per iteration of the KNN scan
#define SAMPLE 2048     // pass-A sample size (global reads, L1-resident)
#define CAND_CAP 96     // per-query candidate buffer (expected use ~34)

typedef unsigned long long u64;

// ---------------------------------------------------------------------------
// Kernel 1 (fused): blocks 0..63 pack coords -> float4{x,y,z,|p|^2};
// blocks 64..319 transpose the four weight matrices: WT[c][o] = W[o][c].
// ---------------------------------------------------------------------------
__global__ __launch_bounds__(256) void prep_and_transpose(
    const float* __restrict__ coords, float4* __restrict__ c4,
    const float* __restrict__ Wq, const float* __restrict__ Wk,
    const float* __restrict__ Wv, const float* __restrict__ Wo,
    float* __restrict__ Tq, float* __restrict__ Tk,
    float* __restrict__ Tv, float* __restrict__ To) {
  const int bid = blockIdx.x;
  const int t = threadIdx.x;
  if (bid < 64) {
    int g = bid * 256 + t;
    float x = coords[3 * g + 0];
    float y = coords[3 * g + 1];
    float z = coords[3 * g + 2];
    // same fma ordering as the scan's dot product so self-distance cancels
    float s = fmaf(x, x, fmaf(y, y, z * z));
    c4[g] = make_float4(x, y, z, s);
  } else {
    int g = (bid - 64) * 256 + t;   // 0..65535
    int mat = g >> 14;              // 0..3
    int j = g & 16383;              // dest linear index: j = c*128 + o
    int c = j >> 7, o = j & 127;
    const float* src = (mat == 0) ? Wq : (mat == 1) ? Wk : (mat == 2) ? Wv : Wo;
    float* dst = (mat == 0) ? Tq : (mat == 1) ? Tk : (mat == 2) ? Tv : To;
    dst[j] = src[o * C_DIM + c];
  }
}

// ---------------------------------------------------------------------------
__device__ __forceinline__ void stage_x64(
    float (*Xs)[132], const float* __restrict__ X, int row0, int t) {
  const float4* X4 = (const float4*)(X + (size_t)row0 * C_DIM);
  for (int i = t; i < 64 * 32; i += 256) {
    int r = i >> 5, c4i = i & 31;
    *(float4*)&Xs[r][c4i * 4] = X4[i];
  }
}

// ---------------------------------------------------------------------------
// Kernel 2a: fused q/k/v projection. 512 blocks = 256 row-tiles x 2 col-
// halves, 256 threads. NEW: W is K-chunk-staged in LDS (12 KB) — the old
// direct-from-global W reads had a 96 KB/block footprint vs 32 KB L1, so
// every W load was an ~200cy L2 round-trip that 2 waves/SIMD can't hide.
// LDS total 46 KB -> 3 blocks/CU. FMA order per output unchanged
// (ascending k) -> bitwise-identical results.
// ---------------------------------------------------------------------------
__global__ __launch_bounds__(256) void gemm_qkv(
    const float* __restrict__ X,
    const float* __restrict__ WTq, const float* __restrict__ WTk,
    const float* __restrict__ WTv,
    float* __restrict__ Yq, float* __restrict__ Yk, float* __restrict__ Yv) {
  __shared__ float Xs[64][132];      // 33.8 KB
  __shared__ float Ws[3][16][64];    // 12 KB: K-chunk x 64-col half, 3 mats
  const int t = threadIdx.x;
  const int row0 = (blockIdx.x >> 1) * 64;
  const int ob = (blockIdx.x & 1) * 64;   // which 64-col half

  stage_x64(Xs, X, row0, t);

  const int r0 = (t >> 4) * 4;
  const int o0l = (t & 15) * 4;        // local col within the half
  const int wk = t >> 4;               // staging: K-row within chunk (0..15)

  float aq[4][4], ak[4][4], av[4][4];
#pragma unroll
  for (int i = 0; i < 4; ++i)
#pragma unroll
    for (int j = 0; j < 4; ++j) { aq[i][j] = 0.f; ak[i][j] = 0.f; av[i][j] = 0.f; }

  for (int kc = 0; kc < C_DIM; kc += 16) {
    __syncthreads();   // previous chunk consumed (also covers X staging)
    {
      const size_t gsrc = (size_t)(kc + wk) * C_DIM + ob + o0l;
      *(float4*)&Ws[0][wk][o0l] = *(const float4*)&WTq[gsrc];
      *(float4*)&Ws[1][wk][o0l] = *(const float4*)&WTk[gsrc];
      *(float4*)&Ws[2][wk][o0l] = *(const float4*)&WTv[gsrc];
    }
    __syncthreads();

#pragma unroll
    for (int c = 0; c < 16; c += 4) {
      float xs[4][4];
#pragma unroll
      for (int i = 0; i < 4; ++i) {
        float4 xv = *(const float4*)&Xs[r0 + i][kc + c];
        xs[i][0] = xv.x; xs[i][1] = xv.y; xs[i][2] = xv.z; xs[i][3] = xv.w;
      }
#pragma unroll
      for (int cc = 0; cc < 4; ++cc) {
        float4 qa = *(const float4*)&Ws[0][c + cc][o0l];
        float4 ka = *(const float4*)&Ws[1][c + cc][o0l];
        float4 va = *(const float4*)&Ws[2][c + cc][o0l];
#pragma unroll
        for (int i = 0; i < 4; ++i) {
          float x = xs[i][cc];
          aq[i][0] = fmaf(x, qa.x, aq[i][0]); aq[i][1] = fmaf(x, qa.y, aq[i][1]);
          aq[i][2] = fmaf(x, qa.z, aq[i][2]); aq[i][3] = fmaf(x, qa.w, aq[i][3]);
          ak[i][0] = fmaf(x, ka.x, ak[i][0]); ak[i][1] = fmaf(x, ka.y, ak[i][1]);
          ak[i][2] = fmaf(x, ka.z, ak[i][2]); ak[i][3] = fmaf(x, ka.w, ak[i][3]);
          av[i][0] = fmaf(x, va.x, av[i][0]); av[i][1] = fmaf(x, va.y, av[i][1]);
          av[i][2] = fmaf(x, va.z, av[i][2]); av[i][3] = fmaf(x, va.w, av[i][3]);
        }
      }
    }
  }

#pragma unroll
  for (int i = 0; i < 4; ++i) {
    const size_t yoff = (size_t)(row0 + r0 + i) * C_DIM + ob + o0l;
    *(float4*)&Yq[yoff] = make_float4(aq[i][0], aq[i][1], aq[i][2], aq[i][3]);
    *(float4*)&Yk[yoff] = make_float4(ak[i][0], ak[i][1], ak[i][2], ak[i][3]);
    *(float4*)&Yv[yoff] = make_float4(av[i][0], av[i][1], av[i][2], av[i][3]);
  }
}

// ---------------------------------------------------------------------------
// Kernel 2b: output projection, same LDS-staged-W scheme (37.8 KB -> 4/CU).
// ---------------------------------------------------------------------------
__global__ __launch_bounds__(256) void gemm_xwt(
    const float* __restrict__ X, const float* __restrict__ WT,
    float* __restrict__ Y) {
  __shared__ float Xs[64][132];
  __shared__ float Ws[16][64];
  const int t = threadIdx.x;
  const int row0 = (blockIdx.x >> 1) * 64;
  const int ob = (blockIdx.x & 1) * 64;

  stage_x64(Xs, X, row0, t);

  const int r0 = (t >> 4) * 4;
  const int o0l = (t & 15) * 4;
  const int wk = t >> 4;

  float acc[4][4];
#pragma unroll
  for (int i = 0; i < 4; ++i)
#pragma unroll
    for (int j = 0; j < 4; ++j) acc[i][j] = 0.0f;

  for (int kc = 0; kc < C_DIM; kc += 16) {
    __syncthreads();
    *(float4*)&Ws[wk][o0l] =
        *(const float4*)&WT[(size_t)(kc + wk) * C_DIM + ob + o0l];
    __syncthreads();

#pragma unroll
    for (int c = 0; c < 16; c += 4) {
      float xs[4][4];
#pragma unroll
      for (int i = 0; i < 4; ++i) {
        float4 xv = *(const float4*)&Xs[r0 + i][kc + c];
        xs[i][0] = xv.x; xs[i][1] = xv.y; xs[i][2] = xv.z; xs[i][3] = xv.w;
      }
#pragma unroll
      for (int cc = 0; cc < 4; ++cc) {
        float4 wa = *(const float4*)&Ws[c + cc][o0l];
#pragma unroll
        for (int i = 0; i < 4; ++i) {
          float x = xs[i][cc];
          acc[i][0] = fmaf(x, wa.x, acc[i][0]); acc[i][1] = fmaf(x, wa.y, acc[i][1]);
          acc[i][2] = fmaf(x, wa.z, acc[i][2]); acc[i][3] = fmaf(x, wa.w, acc[i][3]);
        }
      }
    }
  }

#pragma unroll
  for (int i = 0; i < 4; ++i) {
    float* yrow = Y + (size_t)(row0 + r0 + i) * C_DIM + ob + o0l;
    *(float4*)yrow = make_float4(acc[i][0], acc[i][1], acc[i][2], acc[i][3]);
  }
}

// ---------------------------------------------------------------------------
// Kernel 3: fused KNN + attention (unchanged from R12's measured-best):
// sampled-tau pass A (2048 global pts), ballot-compact pass B, exact
// lex-(d2, idx) final select.
// ---------------------------------------------------------------------------
__device__ __forceinline__ u64 wave_min_u64(u64 x) {
#pragma unroll
  for (int off = 32; off > 0; off >>= 1) {
    u64 o = __shfl_xor(x, off, 64);
    x = (o < x) ? o : x;
  }
  return x;
}

// wave 8th-smallest over per-lane ascending pairs (u0 <= u1)
__device__ __forceinline__ float wave_8th_of_top2(float u0, float u1) {
  float m = 0.0f;
#pragma unroll
  for (int r = 0; r < KNN; ++r) {
    m = u0;
#pragma unroll
    for (int off = 32; off > 0; off >>= 1) {
      float o = __shfl_xor(m, off, 64);
      m = fminf(m, o);
    }
    bool mine = (u0 == m);   // every lane holding m pops one element
    u0 = mine ? u1 : u0;
    u1 = mine ? INFINITY : u1;
  }
  return m;
}

__global__ __launch_bounds__(256) void knn_attn(
    const float4* __restrict__ c4,
    const float* __restrict__ q, const float* __restrict__ k,
    const float* __restrict__ v, const float* __restrict__ log_gamma_p,
    float* __restrict__ agg) {
  __shared__ float4 pts[CHUNK];          // 16 KB
  __shared__ u64 cand[4][CAND_CAP];      // 3 KB, per-query candidate buffers

  const int t = threadIdx.x;
  const int wave = t >> 6;
  const int lane = t & 63;
  const int qi = blockIdx.x * 4 + wave;          // blocks never straddle batch
  const int b = qi >> 13;
  const int n = qi & (NPTS - 1);
  const int base = b * NPTS;

  const float4 qp = c4[base + n];   // {x,y,z,|p|^2}
  const u64 lmask = (1ull << lane) - 1ull;

  // ------- pass A: sampled tau (first SAMPLE points, global reads) --------
  float m1 = INFINITY, m2 = INFINITY;
  const float4* cb = c4 + base;
#pragma unroll 4
  for (int it = 0; it < SAMPLE / 64; ++it) {
    const float4 p = cb[it * 64 + lane];
    float dot = fmaf(qp.x, p.x, fmaf(qp.y, p.y, qp.z * p.z));
    float d2 = fmaxf(qp.w + p.w - 2.0f * dot, 0.0f);
    float h = fmaxf(m1, d2); m1 = fminf(m1, d2); m2 = fminf(m2, h);
  }
  // tau >= s8(sample) >= s8(all): exact-safe filter threshold
  const float tau = wave_8th_of_top2(m1, m2);

  // ---------------- pass B: collect candidates <= tau ---------------------
  int cnt = 0;
  for (int ch = 0; ch < NPTS / CHUNK; ++ch) {
    __syncthreads();
    for (int i = t; i < CHUNK; i += 256) pts[i] = c4[base + ch * CHUNK + i];
    __syncthreads();

#pragma unroll
    for (int it = 0; it < CHUNK / 128; ++it) {
      const int ml = it * 128 + lane;
      const float4 pa = pts[ml];
      const float4 pb = pts[ml + 64];
      float dota = fmaf(qp.x, pa.x, fmaf(qp.y, pa.y, qp.z * pa.z));
      float dotb = fmaf(qp.x, pb.x, fmaf(qp.y, pb.y, qp.z * pb.z));
      float d2a = fmaxf(qp.w + pa.w - 2.0f * dota, 0.0f);
      float d2b = fmaxf(qp.w + pb.w - 2.0f * dotb, 0.0f);
      bool ga = d2a <= tau;
      bool gb = d2b <= tau;
      u64 mska = __ballot(ga);
      u64 mskb = __ballot(gb);
      if (mska | mskb) {   // rarely-taken, wave-uniform branch
        const unsigned ia = (unsigned)(ch * CHUNK + ml);
        if (ga) {
          int pos = cnt + (int)__popcll(mska & lmask);
          if (pos < CAND_CAP)
            cand[wave][pos] = ((u64)__float_as_uint(d2a) << 32) | ia;
        }
        cnt += (int)__popcll(mska);
        if (gb) {
          int pos = cnt + (int)__popcll(mskb & lmask);
          if (pos < CAND_CAP)
            cand[wave][pos] = ((u64)__float_as_uint(d2b) << 32) | (ia + 64);
        }
        cnt += (int)__popcll(mskb);
      }
    }
  }

  // ------- final exact top-8 over candidates (lex (d2, idx)), 2 keys/lane -
  const int m_ = (cnt < CAND_CAP) ? cnt : CAND_CAP;
  u64 a = (lane < m_) ? cand[wave][lane] : ~0ull;
  u64 bb = (lane + 64 < m_) ? cand[wave][lane + 64] : ~0ull;
  u64 k0 = (a < bb) ? a : bb, k1 = (a < bb) ? bb : a;
  int ni_[KNN];
#pragma unroll
  for (int r = 0; r < KNN; ++r) {
    u64 mm = wave_min_u64(k0);
    ni_[r] = (int)(unsigned)(mm & 0xFFFFFFFFu);
    if (k0 == mm) { k0 = k1; k1 = ~0ull; }   // keys unique: owner pops
  }

  // ---- attention over the 8 neighbors (output is order-invariant) ----
  const float lg = *log_gamma_p;
  const size_t qrow = (size_t)(base + n) * C_DIM;
  const float qv0 = q[qrow + lane];
  const float qv1 = q[qrow + lane + 64];

  float score[KNN];
#pragma unroll
  for (int j = 0; j < KNN; ++j) {
    const int mj = ni_[j];
    const size_t krow = (size_t)(base + mj) * C_DIM;
    float p = fmaf(qv1, k[krow + lane + 64], qv0 * k[krow + lane]);
#pragma unroll
    for (int off = 32; off > 0; off >>= 1) p += __shfl_xor(p, off, 64);
    // gamma from the diff-based safe norm (reference's second formula)
    const float4 pm = c4[base + mj];
    float dx = qp.x - pm.x, dy = qp.y - pm.y, dz = qp.z - pm.z;
    float d2p = fmaf(dx, dx, fmaf(dy, dy, dz * dz));
    float dist = d2p > 0.0f ? sqrtf(d2p) : 0.0f;
    float gw = expf(lg * dist);
    score[j] = (p / 11.313708498984761f) * gw;   // /sqrt(128) then *gamma
  }

  float mx = score[0];
#pragma unroll
  for (int j = 1; j < KNN; ++j) mx = fmaxf(mx, score[j]);
  float w[KNN]; float sum = 0.0f;
#pragma unroll
  for (int j = 0; j < KNN; ++j) { w[j] = expf(score[j] - mx); sum += w[j]; }
#pragma unroll
  for (int j = 0; j < KNN; ++j) w[j] = w[j] / sum;

  float a0 = 0.0f, a1 = 0.0f;
#pragma unroll
  for (int j = 0; j < KNN; ++j) {
    const size_t vrow = (size_t)(base + ni_[j]) * C_DIM;
    a0 = fmaf(w[j], v[vrow + lane], a0);
    a1 = fmaf(w[j], v[vrow + lane + 64], a1);
  }
  // agg aliases q's storage: safe, each q row is read only by its own wave
  agg[qrow + lane] = a0;
  agg[qrow + lane + 64] = a1;
}

// ---------------------------------------------------------------------------
extern "C" void kernel_launch(void* const* d_in, const int* in_sizes, int n_in,
                              void* d_out, int out_size, void* d_ws, size_t ws_size,
                              hipStream_t stream) {
  const float* feats  = (const float*)d_in[0];
  const float* coords = (const float*)d_in[1];
  const float* Wq     = (const float*)d_in[2];
  const float* Wk     = (const float*)d_in[3];
  const float* Wv     = (const float*)d_in[4];
  const float* Wo     = (const float*)d_in[5];
  const float* lg     = (const float*)d_in[6];
  float* out = (float*)d_out;

  float* ws = (float*)d_ws;
  const size_t ROWS = (size_t)M_TOTAL * C_DIM;   // 2,097,152 floats
  float*  q   = ws;                               // 8 MB
  float*  k   = ws + ROWS;                        // 8 MB
  float*  v   = ws + 2 * ROWS;                    // 8 MB
  float4* c4  = (float4*)(ws + 3 * ROWS);         // 256 KB, 16B-aligned
  float*  WTq = ws + 3 * ROWS + 4 * (size_t)M_TOTAL;
  float*  WTk = WTq + C_DIM * C_DIM;
  float*  WTv = WTk + C_DIM * C_DIM;
  float*  WTo = WTv + C_DIM * C_DIM;              // total ws use: ~24.8 MB
  float*  agg = q;                                // reuse q's buffer

  prep_and_transpose<<<320, 256, 0, stream>>>(coords, c4, Wq, Wk, Wv, Wo,
                                              WTq, WTk, WTv, WTo);
  gemm_qkv<<<M_TOTAL / 32, 256, 0, stream>>>(feats, WTq, WTk, WTv, q, k, v);
  knn_attn<<<M_TOTAL / 4, 256, 0, stream>>>(c4, q, k, v, lg, agg);
  gemm_xwt<<<M_TOTAL / 32, 256, 0, stream>>>(agg, WTo, out);
}

// Round 15
// 183.228 us; speedup vs baseline: 1.3362x; 1.0564x over previous
//
#include <hip/hip_runtime.h>
#include <math.h>

#define C_DIM 128
#define KNN 8
#define NPTS 8192
#define M_TOTAL 16384   // B*N
#define CHUNK 1024      // points staged in LDS per iteration of the KNN scan
#define SAMPLE 2048     // pass-A sample size (global reads, L1-resident)
#define CAND_CAP 96     // per-query candidate buffer (expected use ~34)

typedef unsigned long long u64;
typedef __attribute__((ext_vector_type(8))) short bf16x8;
typedef __attribute__((ext_vector_type(4))) float f32x4;

// float -> bf16 (round-to-nearest-even), branchless
__device__ __forceinline__ short f2bf(float f) {
  unsigned u = __float_as_uint(f);
  unsigned r = (u + 0x7FFFu + ((u >> 16) & 1u)) >> 16;
  return (short)r;
}

// ---------------------------------------------------------------------------
// Kernel 1 (fused prep):
//   blocks   0..63 : coords -> float4{x,y,z,|p|^2}
//   blocks  64..127: WTo[c][o] = Wo[o][c]        (fp32, for fp32 xwt)
//   blocks 128..319: Wq/Wk/Wv -> bf16, ORIGINAL (o,c) layout (for MFMA B)
// ---------------------------------------------------------------------------
__global__ __launch_bounds__(256) void prep_all(
    const float* __restrict__ coords, float4* __restrict__ c4,
    const float* __restrict__ Wq, const float* __restrict__ Wk,
    const float* __restrict__ Wv, const float* __restrict__ Wo,
    float* __restrict__ To,
    short* __restrict__ Wqb, short* __restrict__ Wkb, short* __restrict__ Wvb) {
  const int bid = blockIdx.x;
  const int t = threadIdx.x;
  if (bid < 64) {
    int g = bid * 256 + t;
    float x = coords[3 * g + 0];
    float y = coords[3 * g + 1];
    float z = coords[3 * g + 2];
    // same fma ordering as the scan's dot product so self-distance cancels
    float s = fmaf(x, x, fmaf(y, y, z * z));
    c4[g] = make_float4(x, y, z, s);
  } else if (bid < 128) {
    int j = (bid - 64) * 256 + t;   // 0..16383, j = c*128 + o
    int c = j >> 7, o = j & 127;
    To[j] = Wo[o * C_DIM + c];
  } else {
    int g = (bid - 128) * 256 + t;  // 0..49151
    int mat = g >> 14;              // 0..2
    int j = g & 16383;
    const float* src = (mat == 0) ? Wq : (mat == 1) ? Wk : Wv;
    short* dst = (mat == 0) ? Wqb : (mat == 1) ? Wkb : Wvb;
    dst[j] = f2bf(src[j]);
  }
}

// ---------------------------------------------------------------------------
// Kernel 2a: q/k/v projection via bf16 MFMA (mfma_f32_16x16x32_bf16).
// 256 blocks x 64 rows x full N=128. 4 waves in 2x2: wave tile 32 rows x
// 64 cols = 2 A-frags x 4 B-frags x 3 mats, K-loop 4 x 32.
// A: feats fp32 -> bf16 during LDS staging (pad 136 -> 16B-aligned frags).
// B: W bf16 in original (o,c) layout -> frag = W[n][k..k+7], 16 contiguous
//    bytes, direct global (L2-hot, 96 KB total).
// C: fp32 accum (f32x4 per frag: col=lane&15, row=(lane>>4)*4+j  [m89]).
// Distances/attention unaffected; only q/k/v values carry bf16 rounding.
// ---------------------------------------------------------------------------
__global__ __launch_bounds__(256) void gemm_qkv_mfma(
    const float* __restrict__ X,
    const short* __restrict__ Wqb, const short* __restrict__ Wkb,
    const short* __restrict__ Wvb,
    float* __restrict__ Yq, float* __restrict__ Yk, float* __restrict__ Yv) {
  __shared__ short As[64][136];   // 17.4 KB, bf16 A tile
  const int t = threadIdx.x;
  const int wave = t >> 6;
  const int lane = t & 63;
  const int row0 = blockIdx.x * 64;

  // stage + convert X tile (64 x 128 fp32 -> bf16)
  const float4* X4 = (const float4*)(X + (size_t)row0 * C_DIM);
  for (int i = t; i < 64 * 32; i += 256) {
    int r = i >> 5, c = i & 31;
    float4 v = X4[i];
    short4 s = make_short4(f2bf(v.x), f2bf(v.y), f2bf(v.z), f2bf(v.w));
    *(short4*)&As[r][c * 4] = s;
  }
  __syncthreads();

  const int wm = wave >> 1;        // 0..1: row half
  const int wn = wave & 1;         // 0..1: col half
  const int l15 = lane & 15;
  const int koff = (lane >> 4) * 8;
  const int arow = wm * 32 + l15;

  f32x4 acc[3][2][4];
#pragma unroll
  for (int m = 0; m < 3; ++m)
#pragma unroll
    for (int i = 0; i < 2; ++i)
#pragma unroll
      for (int j = 0; j < 4; ++j) acc[m][i][j] = (f32x4){0.f, 0.f, 0.f, 0.f};

  const short* Wb[3] = {Wqb, Wkb, Wvb};

#pragma unroll
  for (int kk = 0; kk < C_DIM; kk += 32) {
    bf16x8 a0 = *(const bf16x8*)&As[arow][kk + koff];
    bf16x8 a1 = *(const bf16x8*)&As[arow + 16][kk + koff];
#pragma unroll
    for (int m = 0; m < 3; ++m) {
#pragma unroll
      for (int fn = 0; fn < 4; ++fn) {
        const int n = wn * 64 + fn * 16 + l15;
        bf16x8 b = *(const bf16x8*)&Wb[m][n * C_DIM + kk + koff];
        acc[m][0][fn] =
            __builtin_amdgcn_mfma_f32_16x16x32_bf16(a0, b, acc[m][0][fn], 0, 0, 0);
        acc[m][1][fn] =
            __builtin_amdgcn_mfma_f32_16x16x32_bf16(a1, b, acc[m][1][fn], 0, 0, 0);
      }
    }
  }

  // epilogue: C layout col = lane&15, row = (lane>>4)*4 + j
  float* Y[3] = {Yq, Yk, Yv};
#pragma unroll
  for (int m = 0; m < 3; ++m) {
#pragma unroll
    for (int fm = 0; fm < 2; ++fm) {
      const int rbase = row0 + wm * 32 + fm * 16 + (lane >> 4) * 4;
#pragma unroll
      for (int fn = 0; fn < 4; ++fn) {
        const int col = wn * 64 + fn * 16 + l15;
#pragma unroll
        for (int j = 0; j < 4; ++j)
          Y[m][(size_t)(rbase + j) * C_DIM + col] = acc[m][fm][fn][j];
      }
    }
  }
}

// ---------------------------------------------------------------------------
__device__ __forceinline__ void stage_x64(
    float (*Xs)[132], const float* __restrict__ X, int row0, int t) {
  const float4* X4 = (const float4*)(X + (size_t)row0 * C_DIM);
  for (int i = t; i < 64 * 32; i += 256) {
    int r = i >> 5, c4i = i & 31;
    *(float4*)&Xs[r][c4i * 4] = X4[i];
  }
}

// ---------------------------------------------------------------------------
// Kernel 2b: output projection, fp32 (precision hedge), LDS-staged W
// (R13 measured version, unchanged).
// ---------------------------------------------------------------------------
__global__ __launch_bounds__(256) void gemm_xwt(
    const float* __restrict__ X, const float* __restrict__ WT,
    float* __restrict__ Y) {
  __shared__ float Xs[64][132];
  __shared__ float Ws[16][64];
  const int t = threadIdx.x;
  const int row0 = (blockIdx.x >> 1) * 64;
  const int ob = (blockIdx.x & 1) * 64;

  stage_x64(Xs, X, row0, t);

  const int r0 = (t >> 4) * 4;
  const int o0l = (t & 15) * 4;
  const int wk = t >> 4;

  float acc[4][4];
#pragma unroll
  for (int i = 0; i < 4; ++i)
#pragma unroll
    for (int j = 0; j < 4; ++j) acc[i][j] = 0.0f;

  for (int kc = 0; kc < C_DIM; kc += 16) {
    __syncthreads();
    *(float4*)&Ws[wk][o0l] =
        *(const float4*)&WT[(size_t)(kc + wk) * C_DIM + ob + o0l];
    __syncthreads();

#pragma unroll
    for (int c = 0; c < 16; c += 4) {
      float xs[4][4];
#pragma unroll
      for (int i = 0; i < 4; ++i) {
        float4 xv = *(const float4*)&Xs[r0 + i][kc + c];
        xs[i][0] = xv.x; xs[i][1] = xv.y; xs[i][2] = xv.z; xs[i][3] = xv.w;
      }
#pragma unroll
      for (int cc = 0; cc < 4; ++cc) {
        float4 wa = *(const float4*)&Ws[c + cc][o0l];
#pragma unroll
        for (int i = 0; i < 4; ++i) {
          float x = xs[i][cc];
          acc[i][0] = fmaf(x, wa.x, acc[i][0]); acc[i][1] = fmaf(x, wa.y, acc[i][1]);
          acc[i][2] = fmaf(x, wa.z, acc[i][2]); acc[i][3] = fmaf(x, wa.w, acc[i][3]);
        }
      }
    }
  }

#pragma unroll
  for (int i = 0; i < 4; ++i) {
    float* yrow = Y + (size_t)(row0 + r0 + i) * C_DIM + ob + o0l;
    *(float4*)yrow = make_float4(acc[i][0], acc[i][1], acc[i][2], acc[i][3]);
  }
}

// ---------------------------------------------------------------------------
// Kernel 3: fused KNN + attention (R12/R13 measured-best, unchanged):
// sampled-tau pass A (2048 global pts), ballot-compact pass B, exact
// lex-(d2, idx) final select. Distances fp32 -> indices identical.
// ---------------------------------------------------------------------------
__device__ __forceinline__ u64 wave_min_u64(u64 x) {
#pragma unroll
  for (int off = 32; off > 0; off >>= 1) {
    u64 o = __shfl_xor(x, off, 64);
    x = (o < x) ? o : x;
  }
  return x;
}

// wave 8th-smallest over per-lane ascending pairs (u0 <= u1)
__device__ __forceinline__ float wave_8th_of_top2(float u0, float u1) {
  float m = 0.0f;
#pragma unroll
  for (int r = 0; r < KNN; ++r) {
    m = u0;
#pragma unroll
    for (int off = 32; off > 0; off >>= 1) {
      float o = __shfl_xor(m, off, 64);
      m = fminf(m, o);
    }
    bool mine = (u0 == m);   // every lane holding m pops one element
    u0 = mine ? u1 : u0;
    u1 = mine ? INFINITY : u1;
  }
  return m;
}

__global__ __launch_bounds__(256) void knn_attn(
    const float4* __restrict__ c4,
    const float* __restrict__ q, const float* __restrict__ k,
    const float* __restrict__ v, const float* __restrict__ log_gamma_p,
    float* __restrict__ agg) {
  __shared__ float4 pts[CHUNK];          // 16 KB
  __shared__ u64 cand[4][CAND_CAP];      // 3 KB, per-query candidate buffers

  const int t = threadIdx.x;
  const int wave = t >> 6;
  const int lane = t & 63;
  const int qi = blockIdx.x * 4 + wave;          // blocks never straddle batch
  const int b = qi >> 13;
  const int n = qi & (NPTS - 1);
  const int base = b * NPTS;

  const float4 qp = c4[base + n];   // {x,y,z,|p|^2}
  const u64 lmask = (1ull << lane) - 1ull;

  // ------- pass A: sampled tau (first SAMPLE points, global reads) --------
  float m1 = INFINITY, m2 = INFINITY;
  const float4* cb = c4 + base;
#pragma unroll 4
  for (int it = 0; it < SAMPLE / 64; ++it) {
    const float4 p = cb[it * 64 + lane];
    float dot = fmaf(qp.x, p.x, fmaf(qp.y, p.y, qp.z * p.z));
    float d2 = fmaxf(qp.w + p.w - 2.0f * dot, 0.0f);
    float h = fmaxf(m1, d2); m1 = fminf(m1, d2); m2 = fminf(m2, h);
  }
  // tau >= s8(sample) >= s8(all): exact-safe filter threshold
  const float tau = wave_8th_of_top2(m1, m2);

  // ---------------- pass B: collect candidates <= tau ---------------------
  int cnt = 0;
  for (int ch = 0; ch < NPTS / CHUNK; ++ch) {
    __syncthreads();
    for (int i = t; i < CHUNK; i += 256) pts[i] = c4[base + ch * CHUNK + i];
    __syncthreads();

#pragma unroll
    for (int it = 0; it < CHUNK / 128; ++it) {
      const int ml = it * 128 + lane;
      const float4 pa = pts[ml];
      const float4 pb = pts[ml + 64];
      float dota = fmaf(qp.x, pa.x, fmaf(qp.y, pa.y, qp.z * pa.z));
      float dotb = fmaf(qp.x, pb.x, fmaf(qp.y, pb.y, qp.z * pb.z));
      float d2a = fmaxf(qp.w + pa.w - 2.0f * dota, 0.0f);
      float d2b = fmaxf(qp.w + pb.w - 2.0f * dotb, 0.0f);
      bool ga = d2a <= tau;
      bool gb = d2b <= tau;
      u64 mska = __ballot(ga);
      u64 mskb = __ballot(gb);
      if (mska | mskb) {   // rarely-taken, wave-uniform branch
        const unsigned ia = (unsigned)(ch * CHUNK + ml);
        if (ga) {
          int pos = cnt + (int)__popcll(mska & lmask);
          if (pos < CAND_CAP)
            cand[wave][pos] = ((u64)__float_as_uint(d2a) << 32) | ia;
        }
        cnt += (int)__popcll(mska);
        if (gb) {
          int pos = cnt + (int)__popcll(mskb & lmask);
          if (pos < CAND_CAP)
            cand[wave][pos] = ((u64)__float_as_uint(d2b) << 32) | (ia + 64);
        }
        cnt += (int)__popcll(mskb);
      }
    }
  }

  // ------- final exact top-8 over candidates (lex (d2, idx)), 2 keys/lane -
  const int m_ = (cnt < CAND_CAP) ? cnt : CAND_CAP;
  u64 a = (lane < m_) ? cand[wave][lane] : ~0ull;
  u64 bb = (lane + 64 < m_) ? cand[wave][lane + 64] : ~0ull;
  u64 k0 = (a < bb) ? a : bb, k1 = (a < bb) ? bb : a;
  int ni_[KNN];
#pragma unroll
  for (int r = 0; r < KNN; ++r) {
    u64 mm = wave_min_u64(k0);
    ni_[r] = (int)(unsigned)(mm & 0xFFFFFFFFu);
    if (k0 == mm) { k0 = k1; k1 = ~0ull; }   // keys unique: owner pops
  }

  // ---- attention over the 8 neighbors (output is order-invariant) ----
  const float lg = *log_gamma_p;
  const size_t qrow = (size_t)(base + n) * C_DIM;
  const float qv0 = q[qrow + lane];
  const float qv1 = q[qrow + lane + 64];

  float score[KNN];
#pragma unroll
  for (int j = 0; j < KNN; ++j) {
    const int mj = ni_[j];
    const size_t krow = (size_t)(base + mj) * C_DIM;
    float p = fmaf(qv1, k[krow + lane + 64], qv0 * k[krow + lane]);
#pragma unroll
    for (int off = 32; off > 0; off >>= 1) p += __shfl_xor(p, off, 64);
    // gamma from the diff-based safe norm (reference's second formula)
    const float4 pm = c4[base + mj];
    float dx = qp.x - pm.x, dy = qp.y - pm.y, dz = qp.z - pm.z;
    float d2p = fmaf(dx, dx, fmaf(dy, dy, dz * dz));
    float dist = d2p > 0.0f ? sqrtf(d2p) : 0.0f;
    float gw = expf(lg * dist);
    score[j] = (p / 11.313708498984761f) * gw;   // /sqrt(128) then *gamma
  }

  float mx = score[0];
#pragma unroll
  for (int j = 1; j < KNN; ++j) mx = fmaxf(mx, score[j]);
  float w[KNN]; float sum = 0.0f;
#pragma unroll
  for (int j = 0; j < KNN; ++j) { w[j] = expf(score[j] - mx); sum += w[j]; }
#pragma unroll
  for (int j = 0; j < KNN; ++j) w[j] = w[j] / sum;

  float a0 = 0.0f, a1 = 0.0f;
#pragma unroll
  for (int j = 0; j < KNN; ++j) {
    const size_t vrow = (size_t)(base + ni_[j]) * C_DIM;
    a0 = fmaf(w[j], v[vrow + lane], a0);
    a1 = fmaf(w[j], v[vrow + lane + 64], a1);
  }
  // agg aliases q's storage: safe, each q row is read only by its own wave
  agg[qrow + lane] = a0;
  agg[qrow + lane + 64] = a1;
}

// ---------------------------------------------------------------------------
extern "C" void kernel_launch(void* const* d_in, const int* in_sizes, int n_in,
                              void* d_out, int out_size, void* d_ws, size_t ws_size,
                              hipStream_t stream) {
  const float* feats  = (const float*)d_in[0];
  const float* coords = (const float*)d_in[1];
  const float* Wq     = (const float*)d_in[2];
  const float* Wk     = (const float*)d_in[3];
  const float* Wv     = (const float*)d_in[4];
  const float* Wo     = (const float*)d_in[5];
  const float* lg     = (const float*)d_in[6];
  float* out = (float*)d_out;

  float* ws = (float*)d_ws;
  const size_t ROWS = (size_t)M_TOTAL * C_DIM;   // 2,097,152 floats
  float*  q   = ws;                               // 8 MB
  float*  k   = ws + ROWS;                        // 8 MB
  float*  v   = ws + 2 * ROWS;                    // 8 MB
  float4* c4  = (float4*)(ws + 3 * ROWS);         // 256 KB, 16B-aligned
  float*  WTo = ws + 3 * ROWS + 4 * (size_t)M_TOTAL;   // 64 KB fp32
  short*  Wqb = (short*)(WTo + C_DIM * C_DIM);    // 3 x 32 KB bf16
  short*  Wkb = Wqb + C_DIM * C_DIM;
  short*  Wvb = Wkb + C_DIM * C_DIM;
  float*  agg = q;                                // reuse q's buffer

  prep_all<<<320, 256, 0, stream>>>(coords, c4, Wq, Wk, Wv, Wo,
                                    WTo, Wqb, Wkb, Wvb);
  gemm_qkv_mfma<<<M_TOTAL / 64, 256, 0, stream>>>(feats, Wqb, Wkb, Wvb,
                                                  q, k, v);
  knn_attn<<<M_TOTAL / 4, 256, 0, stream>>>(c4, q, k, v, lg, agg);
  gemm_xwt<<<M_TOTAL / 32, 256, 0, stream>>>(agg, WTo, out);
}